// Round 1
// baseline (170.452 us; speedup 1.0000x reference)
//
#include <hip/hip_runtime.h>
#include <stdint.h>

#define KWORDS 128   // 4096 bits / 32 per row
#define TILE 64

// ---------------------------------------------------------------------------
// Binarize: wave of 64 lanes reads 64 consecutive floats, ballot(v>0) gives a
// 64-bit mask in exact lane order; lane 0 stores the u64. Read-BW bound.
// ---------------------------------------------------------------------------
__global__ __launch_bounds__(256) void binarize64(const float* __restrict__ in,
                                                  unsigned long long* __restrict__ out,
                                                  int n64) {
    const int tid   = blockIdx.x * blockDim.x + threadIdx.x;
    const int lane  = threadIdx.x & 63;
    const int wave  = tid >> 6;
    const int nwav  = (gridDim.x * blockDim.x) >> 6;
    for (int w = wave; w < n64; w += nwav) {
        float v = in[(size_t)w * 64 + lane];
        unsigned long long m = __ballot(v > 0.0f);
        if (lane == 0) out[w] = m;
    }
}

// ---------------------------------------------------------------------------
// Binary GEMM: C[i][j] = 4096 - 2 * popcount(xb[i] ^ wb[j])
// 64x64 output tile per block, full K staged in LDS once (no K-loop barrier).
// 256 threads as 16x16, each computes a 4x4 micro-tile.
// LDS layout XOR-swizzled at uint4 granularity: chunk' = chunk ^ ((row>>2)&7)
// -> B-operand reads (16 distinct rows per wave) spread across all 32 banks.
// ---------------------------------------------------------------------------
__global__ __launch_bounds__(256, 2) void xnor_gemm(const uint32_t* __restrict__ xb,
                                                    const uint32_t* __restrict__ wb,
                                                    float* __restrict__ out) {
    __shared__ uint32_t lxa[TILE * KWORDS];   // 32 KB
    __shared__ uint32_t lwb[TILE * KWORDS];   // 32 KB

    const int tid  = threadIdx.x;
    const int brow = blockIdx.y;   // token-tile
    const int bcol = blockIdx.x;   // out-feature-tile

    // ---- stage both tiles (full K), coalesced uint4 loads -----------------
    // 64 rows x 32 uint4-chunks = 2048 chunks per matrix; 8 iters per thread.
    for (int idx = tid; idx < TILE * 32; idx += 256) {
        const int r   = idx >> 5;
        const int cw  = idx & 31;
        const int pcw = cw ^ ((r >> 2) & 7);          // XOR swizzle
        const uint4 va = *(const uint4*)(xb + ((size_t)(brow * TILE + r) * KWORDS + cw * 4));
        *(uint4*)(lxa + r * KWORDS + pcw * 4) = va;
        const uint4 vb = *(const uint4*)(wb + ((size_t)(bcol * TILE + r) * KWORDS + cw * 4));
        *(uint4*)(lwb + r * KWORDS + pcw * 4) = vb;
    }
    __syncthreads();

    const int tx = tid & 15;       // out-feature group (4 cols)
    const int ty = tid >> 4;       // token group (4 rows)

    uint32_t acc[4][4];
#pragma unroll
    for (int r = 0; r < 4; ++r)
#pragma unroll
        for (int c = 0; c < 4; ++c) acc[r][c] = 0;

    const uint32_t* pa = lxa + ty * 4 * KWORDS;
    const uint32_t* pb = lwb + tx * 4 * KWORDS;
    const int ka = ty & 7;         // (row>>2)&7 for rows ty*4..ty*4+3
    const int kb = tx & 7;

#pragma unroll 4
    for (int w = 0; w < 32; ++w) {
        const int sa = ((w ^ ka) << 2);
        const int sb = ((w ^ kb) << 2);
        uint4 a[4], b[4];
#pragma unroll
        for (int r = 0; r < 4; ++r) a[r] = *(const uint4*)(pa + r * KWORDS + sa);
#pragma unroll
        for (int c = 0; c < 4; ++c) b[c] = *(const uint4*)(pb + c * KWORDS + sb);
#pragma unroll
        for (int r = 0; r < 4; ++r) {
#pragma unroll
            for (int c = 0; c < 4; ++c) {
                acc[r][c] += __popc(a[r].x ^ b[c].x);   // -> v_xor + v_bcnt(acc)
                acc[r][c] += __popc(a[r].y ^ b[c].y);
                acc[r][c] += __popc(a[r].z ^ b[c].z);
                acc[r][c] += __popc(a[r].w ^ b[c].w);
            }
        }
    }

    // ---- epilogue: dot = K - 2*popc, float4 stores -------------------------
    const size_t N = 4096;
    const int gcol = bcol * TILE + tx * 4;
#pragma unroll
    for (int r = 0; r < 4; ++r) {
        const size_t grow = (size_t)(brow * TILE + ty * 4 + r);
        float4 o;
        o.x = (float)(4096 - 2 * (int)acc[r][0]);
        o.y = (float)(4096 - 2 * (int)acc[r][1]);
        o.z = (float)(4096 - 2 * (int)acc[r][2]);
        o.w = (float)(4096 - 2 * (int)acc[r][3]);
        *(float4*)(out + grow * N + gcol) = o;
    }
}

extern "C" void kernel_launch(void* const* d_in, const int* in_sizes, int n_in,
                              void* d_out, int out_size, void* d_ws, size_t ws_size,
                              hipStream_t stream) {
    const float* x = (const float*)d_in[0];   // [4096, 4096]
    const float* W = (const float*)d_in[1];   // [4096, 4096] (out, in)
    float* out = (float*)d_out;               // [4096, 4096] f32

    uint32_t* xb = (uint32_t*)d_ws;           // 2 MB
    uint32_t* wb = xb + (size_t)4096 * KWORDS; // next 2 MB

    const int n64 = 4096 * 4096 / 64;         // 262144 u64 words per matrix
    binarize64<<<2048, 256, 0, stream>>>(x, (unsigned long long*)xb, n64);
    binarize64<<<2048, 256, 0, stream>>>(W, (unsigned long long*)wb, n64);

    dim3 grid(4096 / TILE, 4096 / TILE);      // 64 x 64 blocks
    xnor_gemm<<<grid, 256, 0, stream>>>(xb, wb, out);
}